// Round 3
// baseline (1656.149 us; speedup 1.0000x reference)
//
#include <hip/hip_runtime.h>
#include <stdint.h>
#include <math.h>

// FuXi block on MI355X, round 3: all-fp32 I/O (per reference dtypes), fp32 compute.
// Rounds 1-2 NaN'd by misreading fp32 inputs as bf16. Workspace: 3 fp32
// [4096,1024] buffers = 48 MB; d_out (fp32, 16 MB) doubles as scratch (v, then o).

#define D    1024
#define NH   16
#define DH   64
#define B_   2
#define S_   2048
#define ROWS 4096          // B_*S_
#define EPSR 1e-8f

__device__ __forceinline__ float silu_f(float v) { return v / (1.0f + __expf(-v)); }

// ---------------- RMSNorm: one block (256 thr) per row, d=1024 ----------------
// out = in * rsqrt(mean(in^2)+eps) * g * (mul ? mul : 1)
__global__ __launch_bounds__(256) void rmsnorm_kernel(
    const float* __restrict__ in, const float* __restrict__ g,
    const float* __restrict__ mul, float* __restrict__ out)
{
    const int row = blockIdx.x;
    const int tid = threadIdx.x;
    const size_t base = (size_t)row * D;
    const int c = tid << 2;
    float4 x = *(const float4*)&in[base + c];
    float ss = x.x*x.x + x.y*x.y + x.z*x.z + x.w*x.w;
#pragma unroll
    for (int off = 32; off > 0; off >>= 1) ss += __shfl_down(ss, off, 64);
    __shared__ float red[4];
    if ((tid & 63) == 0) red[tid >> 6] = ss;
    __syncthreads();
    float r = rsqrtf((red[0] + red[1] + red[2] + red[3]) * (1.0f / D) + EPSR);
    float4 gv = *(const float4*)&g[c];
    float4 o;
    o.x = x.x * r * gv.x; o.y = x.y * r * gv.y;
    o.z = x.z * r * gv.z; o.w = x.w * r * gv.w;
    if (mul) {
        float4 m = *(const float4*)&mul[base + c];
        o.x *= m.x; o.y *= m.y; o.z *= m.z; o.w *= m.w;
    }
    *(float4*)&out[base + c] = o;
}

// ---------------- GEMM: C[4096,*] = A[4096,1024] @ Bw[1024,ldb] + bias ----------------
// 64x64 tile, KT=16, 256 threads, 4x4 micro-tile, LDS pitch 68 (16B-aligned rows,
// 2-way bank alias = free). Epilogue: +bias, optional silu, optional fp32 residual.
// res may alias out (same-thread read-then-write, disjoint tiles across blocks).
__global__ __launch_bounds__(256) void gemm_kernel(
    const float* __restrict__ A, const float* __restrict__ Bw,
    const float* __restrict__ bias, const float* __restrict__ res,
    float* __restrict__ out, int ldb, int act)
{
    __shared__ float As[16][68];   // [k][m]
    __shared__ float Bs[16][68];   // [k][n]
    const int tid = threadIdx.x;
    const int tx = tid & 15, ty = tid >> 4;
    const int row0 = blockIdx.y << 6;
    const int col0 = blockIdx.x << 6;

    const int ar = tid >> 2;          // 0..63 (m)
    const int ak = (tid & 3) << 2;    // 0,4,8,12 (k)
    const int bn = (tid & 15) << 2;   // 0..60 (n)
    const int bk = tid >> 4;          // 0..15 (k)

    float acc[4][4] = {};

    for (int k0 = 0; k0 < D; k0 += 16) {
        float4 a4 = *(const float4*)&A[(size_t)(row0 + ar) * D + k0 + ak];
        float4 b4 = *(const float4*)&Bw[(size_t)(k0 + bk) * ldb + col0 + bn];
        __syncthreads();   // prev-iter LDS reads done
        As[ak + 0][ar] = a4.x; As[ak + 1][ar] = a4.y;
        As[ak + 2][ar] = a4.z; As[ak + 3][ar] = a4.w;
        *(float4*)&Bs[bk][bn] = b4;
        __syncthreads();
#pragma unroll
        for (int kk = 0; kk < 16; ++kk) {
            float4 av = *(const float4*)&As[kk][ty << 2];
            float4 bv = *(const float4*)&Bs[kk][tx << 2];
            float a[4] = {av.x, av.y, av.z, av.w};
            float b[4] = {bv.x, bv.y, bv.z, bv.w};
#pragma unroll
            for (int i = 0; i < 4; ++i)
#pragma unroll
                for (int j = 0; j < 4; ++j)
                    acc[i][j] = fmaf(a[i], b[j], acc[i][j]);
        }
    }
#pragma unroll
    for (int i = 0; i < 4; ++i) {
        const int row = row0 + (ty << 2) + i;
        const size_t rb = (size_t)row * D + col0 + (tx << 2);
        float4 vv;
        vv.x = acc[i][0] + bias[col0 + (tx << 2) + 0];
        vv.y = acc[i][1] + bias[col0 + (tx << 2) + 1];
        vv.z = acc[i][2] + bias[col0 + (tx << 2) + 2];
        vv.w = acc[i][3] + bias[col0 + (tx << 2) + 3];
        if (act) {
            vv.x = silu_f(vv.x); vv.y = silu_f(vv.y);
            vv.z = silu_f(vv.z); vv.w = silu_f(vv.w);
        }
        if (res) {
            float4 r4 = *(const float4*)&res[rb];
            vv.x += r4.x; vv.y += r4.y; vv.z += r4.z; vv.w += r4.w;
        }
        *(float4*)&out[rb] = vv;
    }
}

// ---------------- SiLU attention ----------------
// Per (b,h): out = silu(q @ k^T * 0.125 + pb[t,h]) @ v, tiled 64 s x 64 t.
// No softmax -> plain accumulation over t-tiles. out may alias q (each block
// fully stages its q tile into LDS before writing; block regions disjoint).
__global__ __launch_bounds__(256) void attn_kernel(
    const float* __restrict__ q, const float* __restrict__ k, const float* __restrict__ v,
    const float* __restrict__ pb, float* __restrict__ out)
{
    __shared__ float qT[64][68];   // [dh][s]
    __shared__ float kv[64][68];   // kT: [dh][t], then vv: [t][dh]
    __shared__ float aT[64][68];   // [t][s]
    const int tid = threadIdx.x;
    const int tx = tid & 15, ty = tid >> 4;
    const int s0 = blockIdx.x << 6;
    const int h  = blockIdx.y;
    const int b  = blockIdx.z;
    const size_t base = (size_t)b * S_ * D + (size_t)h * DH;

    const int ls = tid >> 4;          // 0..15
    const int lj = (tid & 15) << 2;   // 0..60

#pragma unroll
    for (int l = 0; l < 4; ++l) {
        int s = ls + (l << 4);
        float4 t4 = *(const float4*)&q[base + (size_t)(s0 + s) * D + lj];
        qT[lj + 0][s] = t4.x; qT[lj + 1][s] = t4.y;
        qT[lj + 2][s] = t4.z; qT[lj + 3][s] = t4.w;
    }

    float acc[4][4] = {};
    for (int t0 = 0; t0 < S_; t0 += 64) {
        __syncthreads();   // prev-iter kv/aT reads done; qT visible (1st iter)
#pragma unroll
        for (int l = 0; l < 4; ++l) {
            int t = ls + (l << 4);
            float4 t4 = *(const float4*)&k[base + (size_t)(t0 + t) * D + lj];
            kv[lj + 0][t] = t4.x; kv[lj + 1][t] = t4.y;
            kv[lj + 2][t] = t4.z; kv[lj + 3][t] = t4.w;
        }
        __syncthreads();
        float sc[4][4] = {};
#pragma unroll
        for (int kk = 0; kk < 64; ++kk) {
            float4 av = *(const float4*)&qT[kk][ty << 2];
            float4 bv = *(const float4*)&kv[kk][tx << 2];
            float a[4] = {av.x, av.y, av.z, av.w};
            float b2[4] = {bv.x, bv.y, bv.z, bv.w};
#pragma unroll
            for (int i = 0; i < 4; ++i)
#pragma unroll
                for (int j = 0; j < 4; ++j)
                    sc[i][j] = fmaf(a[i], b2[j], sc[i][j]);
        }
#pragma unroll
        for (int j = 0; j < 4; ++j) {
            int t = (tx << 2) + j;
            float pbv = pb[(size_t)(t0 + t) * NH + h];
#pragma unroll
            for (int i = 0; i < 4; ++i) {
                float sv = fmaf(sc[i][j], 0.125f, pbv);
                aT[t][(ty << 2) + i] = silu_f(sv);
            }
        }
        __syncthreads();   // kT reads + aT writes done
#pragma unroll
        for (int l = 0; l < 4; ++l) {
            int t = ls + (l << 4);
            *(float4*)&kv[t][lj] = *(const float4*)&v[base + (size_t)(t0 + t) * D + lj];
        }
        __syncthreads();
#pragma unroll
        for (int tt = 0; tt < 64; ++tt) {
            float4 av = *(const float4*)&aT[tt][ty << 2];
            float4 bv = *(const float4*)&kv[tt][tx << 2];
            float a[4] = {av.x, av.y, av.z, av.w};
            float b2[4] = {bv.x, bv.y, bv.z, bv.w};
#pragma unroll
            for (int i = 0; i < 4; ++i)
#pragma unroll
                for (int j = 0; j < 4; ++j)
                    acc[i][j] = fmaf(a[i], b2[j], acc[i][j]);
        }
    }
#pragma unroll
    for (int i = 0; i < 4; ++i) {
        int s = s0 + (ty << 2) + i;
        float4 o4 = make_float4(acc[i][0], acc[i][1], acc[i][2], acc[i][3]);
        *(float4*)&out[base + (size_t)s * D + (tx << 2)] = o4;
    }
}

// ---------------- SwiGLU elementwise: out = silu(x1) * x2 (out may alias x1) ----------------
__global__ __launch_bounds__(256) void swiglu_kernel(
    const float* __restrict__ x1, const float* __restrict__ x2, float* __restrict__ out)
{
    size_t i = ((size_t)blockIdx.x * 256 + threadIdx.x) << 2;
    float4 a = *(const float4*)&x1[i];
    float4 b = *(const float4*)&x2[i];
    float4 r;
    r.x = silu_f(a.x) * b.x;
    r.y = silu_f(a.y) * b.y;
    r.z = silu_f(a.z) * b.z;
    r.w = silu_f(a.w) * b.w;
    *(float4*)&out[i] = r;
}

extern "C" void kernel_launch(void* const* d_in, const int* in_sizes, int n_in,
                              void* d_out, int out_size, void* d_ws, size_t ws_size,
                              hipStream_t stream)
{
    const float* x      = (const float*)d_in[0];
    // d_in[1] = t_bias (unused by the module)
    const float* pb     = (const float*)d_in[2];
    const float* wq     = (const float*)d_in[3];
    const float* bq     = (const float*)d_in[4];
    const float* wk     = (const float*)d_in[5];
    const float* bk     = (const float*)d_in[6];
    const float* wv     = (const float*)d_in[7];
    const float* bv     = (const float*)d_in[8];
    const float* wu     = (const float*)d_in[9];
    const float* bu     = (const float*)d_in[10];
    const float* g_ams  = (const float*)d_in[11];
    const float* w0     = (const float*)d_in[12];
    const float* b0     = (const float*)d_in[13];
    const float* w1     = (const float*)d_in[14];
    const float* b1     = (const float*)d_in[15];
    const float* w2     = (const float*)d_in[16];
    const float* b2     = (const float*)d_in[17];
    const float* g_mffn = (const float*)d_in[18];
    float* OUT = (float*)d_out;            // 16 MB; doubles as scratch (v, then o)

    const size_t BUF = (size_t)ROWS * D;   // 4 Mi floats = 16 MB each
    float* W0 = (float*)d_ws;              // total ws need: 48 MB
    float* W1 = W0 + BUF;
    float* W2 = W1 + BUF;

    dim3 blk(256);
    dim3 gN(D / 64, ROWS / 64);

    // 1. xn = rmsnorm(x)*g_ams -> W0
    rmsnorm_kernel<<<ROWS, blk, 0, stream>>>(x, g_ams, nullptr, W0);
    // 2. q -> W1, k -> W2, v -> OUT
    gemm_kernel<<<gN, blk, 0, stream>>>(W0, wq, bq, nullptr, W1, D, 0);
    gemm_kernel<<<gN, blk, 0, stream>>>(W0, wk, bk, nullptr, W2, D, 0);
    gemm_kernel<<<gN, blk, 0, stream>>>(W0, wv, bv, nullptr, OUT, D, 0);
    // 3. silu-attention(q=W1, k=W2, v=OUT) -> W1 (in-place over q: safe)
    attn_kernel<<<dim3(S_ / 64, NH, B_), blk, 0, stream>>>(W1, W2, OUT, pb, W1);
    // 4. u = silu(xn@wu + bu) -> W2 (k dead)
    gemm_kernel<<<gN, blk, 0, stream>>>(W0, wu, bu, nullptr, W2, D, 1);
    // 5. ams = rmsnorm(attn_out)*g_ams*u -> W0 (xn dead)
    rmsnorm_kernel<<<ROWS, blk, 0, stream>>>(W1, g_ams, W2, W0);
    // 6. o = ams@w0 + b0 + x -> OUT (v dead)
    gemm_kernel<<<gN, blk, 0, stream>>>(W0, w0, b0, x, OUT, D, 0);
    // 7. o_norm = rmsnorm(o)*g_mffn -> W0 (ams dead)
    rmsnorm_kernel<<<ROWS, blk, 0, stream>>>(OUT, g_mffn, nullptr, W0);
    // 8. x1 = o_norm@w1[:, :1024] -> W1 ; x2 = o_norm@w1[:, 1024:] -> W2
    gemm_kernel<<<gN, blk, 0, stream>>>(W0, w1,     b1,     nullptr, W1, 2 * D, 0);
    gemm_kernel<<<gN, blk, 0, stream>>>(W0, w1 + D, b1 + D, nullptr, W2, 2 * D, 0);
    // 9. swiglu = silu(x1)*x2 -> W1 (in-place)
    swiglu_kernel<<<ROWS * D / 1024, blk, 0, stream>>>(W1, W2, W1);
    // 10. out = swiglu@w2 + b2 + o(res=OUT) -> OUT (res aliases out: safe)
    gemm_kernel<<<gN, blk, 0, stream>>>(W1, w2, b2, OUT, OUT, D, 0);
}

// Round 4
// 888.338 us; speedup vs baseline: 1.8643x; 1.8643x over previous
//
#include <hip/hip_runtime.h>
#include <stdint.h>
#include <math.h>

// FuXi block on MI355X, round 4: MFMA bf16 GEMMs (m97 structure), bf16 intermediates,
// fp32 residual path. Attention still fp32-VALU (bf16 I/O); MFMA-attn next round.
// ws: [W^T bf16 16MB][A0..A3 bf16 8MB each] = 48 MB. o + final out live in d_out (fp32).

#define D    1024
#define NH   16
#define DH   64
#define B_   2
#define S_   2048
#define ROWS 4096
#define EPSR 1e-8f

typedef unsigned short u16;
typedef __attribute__((ext_vector_type(8))) short short8;
typedef __attribute__((ext_vector_type(4))) float f32x4;

__device__ __forceinline__ float bf2f(u16 u) {
    union { uint32_t i; float f; } c; c.i = ((uint32_t)u) << 16; return c.f;
}
__device__ __forceinline__ u16 f2bf(float f) {
    union { float f; uint32_t i; } c; c.f = f;
    uint32_t x = c.i;
    x += 0x7fffu + ((x >> 16) & 1u);
    return (u16)(x >> 16);
}
__device__ __forceinline__ float silu_f(float v) { return v / (1.0f + __expf(-v)); }

// ---------------- weight prep: fp32 W[K=1024][N] -> bf16 WT[N][1024] ----------------
__global__ __launch_bounds__(256) void transpose_cast_kernel(
    const float* __restrict__ W, u16* __restrict__ WTo, int N)
{
    __shared__ float T[64][65];
    const int tid = threadIdx.x;
    const int n0 = blockIdx.x << 6;
    const int k0 = blockIdx.y << 6;
    const int rr = tid >> 4;
    const int cc = (tid & 15) << 2;
#pragma unroll
    for (int l = 0; l < 4; ++l) {
        const int r = rr + (l << 4);
        float4 v = *(const float4*)&W[(size_t)(k0 + r) * N + n0 + cc];
        T[cc + 0][r] = v.x; T[cc + 1][r] = v.y;
        T[cc + 2][r] = v.z; T[cc + 3][r] = v.w;
    }
    __syncthreads();
    const int n  = tid >> 2;
    const int ks = (tid & 3) << 4;
#pragma unroll
    for (int m = 0; m < 4; ++m) {
        const int k = ks + (m << 2);
        float4 v = *(const float4*)&T[n][k];
        ushort4 o;
        o.x = f2bf(v.x); o.y = f2bf(v.y); o.z = f2bf(v.z); o.w = f2bf(v.w);
        *(ushort4*)&WTo[(size_t)(n0 + n) * 1024 + k0 + k] = o;
    }
}

// ---------------- RMSNorm: in fp32 OR bf16, optional bf16 mul, out bf16 ----------------
__global__ __launch_bounds__(256) void rmsnorm_kernel(
    const float* __restrict__ inf, const u16* __restrict__ inb,
    const float* __restrict__ g, const u16* __restrict__ mul,
    u16* __restrict__ out)
{
    const int row = blockIdx.x;
    const int tid = threadIdx.x;
    const size_t base = (size_t)row * D;
    const int c = tid << 2;
    float x0, x1, x2, x3;
    if (inb) {
        ushort4 xi = *(const ushort4*)&inb[base + c];
        x0 = bf2f(xi.x); x1 = bf2f(xi.y); x2 = bf2f(xi.z); x3 = bf2f(xi.w);
    } else {
        float4 xi = *(const float4*)&inf[base + c];
        x0 = xi.x; x1 = xi.y; x2 = xi.z; x3 = xi.w;
    }
    float ss = x0*x0 + x1*x1 + x2*x2 + x3*x3;
#pragma unroll
    for (int off = 32; off > 0; off >>= 1) ss += __shfl_down(ss, off, 64);
    __shared__ float red[4];
    if ((tid & 63) == 0) red[tid >> 6] = ss;
    __syncthreads();
    float r = rsqrtf((red[0] + red[1] + red[2] + red[3]) * (1.0f / D) + EPSR);
    float4 gv = *(const float4*)&g[c];
    float v0 = x0 * r * gv.x, v1 = x1 * r * gv.y, v2 = x2 * r * gv.z, v3 = x3 * r * gv.w;
    if (mul) {
        ushort4 mi = *(const ushort4*)&mul[base + c];
        v0 *= bf2f(mi.x); v1 *= bf2f(mi.y); v2 *= bf2f(mi.z); v3 *= bf2f(mi.w);
    }
    ushort4 o;
    o.x = f2bf(v0); o.y = f2bf(v1); o.z = f2bf(v2); o.w = f2bf(v3);
    *(ushort4*)&out[base + c] = o;
}

// ---------------- MFMA GEMM: C[4096,Nout] = A[4096,1024](bf16) @ W ----------------
// WT is bf16 [Nout][1024] (k contiguous -> B-fragment is a ds_read_b128).
// 128x128 tile, BK=32, 4 waves x (4x4 of 16x16x32 MFMA). global_load_lds w=16.
// Epilogue: +bias(fp32), optional silu, optional fp32 residual (may alias outf);
// out bf16 (outb) or fp32 (outf), row stride ldo.
__global__ __launch_bounds__(256) void gemm_mfma(
    const u16* __restrict__ A, const u16* __restrict__ WT,
    const float* __restrict__ bias, const float* __restrict__ res,
    u16* __restrict__ outb, float* __restrict__ outf,
    int ldo, int act)
{
    __shared__ u16 As[128 * 32];
    __shared__ u16 Bs[128 * 32];
    const int tid  = threadIdx.x;
    const int wave = tid >> 6;
    const int lane = tid & 63;
    const int lm   = lane & 15;
    const int quad = lane >> 4;
    const int row0 = blockIdx.y << 7;
    const int col0 = blockIdx.x << 7;
    const int wr = (wave >> 1) << 6;   // wave m-offset (0/64)
    const int wc = (wave & 1) << 6;    // wave n-offset (0/64)

    // staging: wave stages 32 A-rows + 32 WT-rows; each instr = 16 rows (64 lanes x 16B)
    const int srow = wave * 32 + (lane >> 2);
    const int skp  = (lane & 3) << 3;
    const u16* Ag = A  + (size_t)(row0 + srow) * 1024 + skp;
    const u16* Bg = WT + (size_t)(col0 + srow) * 1024 + skp;
    u16* Asd0 = &As[(wave * 32) * 32];        // wave-uniform LDS bases
    u16* Asd1 = &As[(wave * 32 + 16) * 32];
    u16* Bsd0 = &Bs[(wave * 32) * 32];
    u16* Bsd1 = &Bs[(wave * 32 + 16) * 32];

    f32x4 acc[4][4] = {};

    for (int k0 = 0; k0 < 1024; k0 += 32) {
        __syncthreads();   // prev-iter LDS reads done
        __builtin_amdgcn_global_load_lds(
            (const __attribute__((address_space(1))) void*)(Ag + k0),
            (__attribute__((address_space(3))) void*)Asd0, 16, 0, 0);
        __builtin_amdgcn_global_load_lds(
            (const __attribute__((address_space(1))) void*)(Ag + 16 * 1024 + k0),
            (__attribute__((address_space(3))) void*)Asd1, 16, 0, 0);
        __builtin_amdgcn_global_load_lds(
            (const __attribute__((address_space(1))) void*)(Bg + k0),
            (__attribute__((address_space(3))) void*)Bsd0, 16, 0, 0);
        __builtin_amdgcn_global_load_lds(
            (const __attribute__((address_space(1))) void*)(Bg + 16 * 1024 + k0),
            (__attribute__((address_space(3))) void*)Bsd1, 16, 0, 0);
        __syncthreads();   // loads drained + visible
        short8 af[4], bf[4];
#pragma unroll
        for (int i = 0; i < 4; ++i)
            af[i] = *(const short8*)&As[(wr + i * 16 + lm) * 32 + quad * 8];
#pragma unroll
        for (int j = 0; j < 4; ++j)
            bf[j] = *(const short8*)&Bs[(wc + j * 16 + lm) * 32 + quad * 8];
#pragma unroll
        for (int i = 0; i < 4; ++i)
#pragma unroll
            for (int j = 0; j < 4; ++j)
                acc[i][j] = __builtin_amdgcn_mfma_f32_16x16x32_bf16(af[i], bf[j], acc[i][j], 0, 0, 0);
    }
    // epilogue: C/D layout col=lane&15, row=quad*4+reg (verified m89/m91)
#pragma unroll
    for (int j = 0; j < 4; ++j) {
        const int colg = col0 + wc + j * 16 + lm;
        const float bj = bias[colg];
#pragma unroll
        for (int i = 0; i < 4; ++i) {
#pragma unroll
            for (int r = 0; r < 4; ++r) {
                const int rowg = row0 + wr + i * 16 + quad * 4 + r;
                const size_t idx = (size_t)rowg * ldo + colg;
                float v = acc[i][j][r] + bj;
                if (act) v = silu_f(v);
                if (res) v += res[idx];
                if (outf) outf[idx] = v;
                else      outb[idx] = f2bf(v);
            }
        }
    }
}

// ---------------- SiLU attention (fp32 compute, bf16 I/O) ----------------
// Per (b,h): out = silu(q @ k^T * 0.125 + pb[t,h]) @ v, tiled 64 s x 64 t.
// out may alias q (q tile fully staged to LDS first; block regions disjoint).
__global__ __launch_bounds__(256) void attn_kernel(
    const u16* __restrict__ q, const u16* __restrict__ k, const u16* __restrict__ v,
    const float* __restrict__ pb, u16* __restrict__ out)
{
    __shared__ float qT[64][68];
    __shared__ float kv[64][68];
    __shared__ float aT[64][68];
    const int tid = threadIdx.x;
    const int tx = tid & 15, ty = tid >> 4;
    const int s0 = blockIdx.x << 6;
    const int h  = blockIdx.y;
    const int b  = blockIdx.z;
    const size_t base = (size_t)b * S_ * D + (size_t)h * DH;

    const int ls = tid >> 4;
    const int lj = (tid & 15) << 2;

#pragma unroll
    for (int l = 0; l < 4; ++l) {
        int s = ls + (l << 4);
        ushort4 t4 = *(const ushort4*)&q[base + (size_t)(s0 + s) * D + lj];
        qT[lj + 0][s] = bf2f(t4.x); qT[lj + 1][s] = bf2f(t4.y);
        qT[lj + 2][s] = bf2f(t4.z); qT[lj + 3][s] = bf2f(t4.w);
    }

    float acc[4][4] = {};
    for (int t0 = 0; t0 < S_; t0 += 64) {
        __syncthreads();
#pragma unroll
        for (int l = 0; l < 4; ++l) {
            int t = ls + (l << 4);
            ushort4 t4 = *(const ushort4*)&k[base + (size_t)(t0 + t) * D + lj];
            kv[lj + 0][t] = bf2f(t4.x); kv[lj + 1][t] = bf2f(t4.y);
            kv[lj + 2][t] = bf2f(t4.z); kv[lj + 3][t] = bf2f(t4.w);
        }
        __syncthreads();
        float sc[4][4] = {};
#pragma unroll
        for (int kk = 0; kk < 64; ++kk) {
            float4 av = *(const float4*)&qT[kk][ty << 2];
            float4 bv = *(const float4*)&kv[kk][tx << 2];
            float a[4] = {av.x, av.y, av.z, av.w};
            float b2[4] = {bv.x, bv.y, bv.z, bv.w};
#pragma unroll
            for (int i = 0; i < 4; ++i)
#pragma unroll
                for (int j = 0; j < 4; ++j)
                    sc[i][j] = fmaf(a[i], b2[j], sc[i][j]);
        }
#pragma unroll
        for (int j = 0; j < 4; ++j) {
            int t = (tx << 2) + j;
            float pbv = pb[(size_t)(t0 + t) * NH + h];
#pragma unroll
            for (int i = 0; i < 4; ++i) {
                float sv = fmaf(sc[i][j], 0.125f, pbv);
                aT[t][(ty << 2) + i] = silu_f(sv);
            }
        }
        __syncthreads();
#pragma unroll
        for (int l = 0; l < 4; ++l) {
            int t = ls + (l << 4);
            ushort4 t4 = *(const ushort4*)&v[base + (size_t)(t0 + t) * D + lj];
            float4 vf;
            vf.x = bf2f(t4.x); vf.y = bf2f(t4.y); vf.z = bf2f(t4.z); vf.w = bf2f(t4.w);
            *(float4*)&kv[t][lj] = vf;
        }
        __syncthreads();
#pragma unroll
        for (int tt = 0; tt < 64; ++tt) {
            float4 av = *(const float4*)&aT[tt][ty << 2];
            float4 bv = *(const float4*)&kv[tt][tx << 2];
            float a[4] = {av.x, av.y, av.z, av.w};
            float b2[4] = {bv.x, bv.y, bv.z, bv.w};
#pragma unroll
            for (int i = 0; i < 4; ++i)
#pragma unroll
                for (int j = 0; j < 4; ++j)
                    acc[i][j] = fmaf(a[i], b2[j], acc[i][j]);
        }
    }
#pragma unroll
    for (int i = 0; i < 4; ++i) {
        int s = s0 + (ty << 2) + i;
        ushort4 o;
        o.x = f2bf(acc[i][0]); o.y = f2bf(acc[i][1]);
        o.z = f2bf(acc[i][2]); o.w = f2bf(acc[i][3]);
        *(ushort4*)&out[base + (size_t)s * D + (tx << 2)] = o;
    }
}

// ---------------- SwiGLU: x12 bf16 [4096][2048] -> out bf16 [4096][1024] ----------------
__global__ __launch_bounds__(256) void swiglu_kernel(
    const u16* __restrict__ x12, u16* __restrict__ out)
{
    const size_t e = ((size_t)blockIdx.x * 256 + threadIdx.x) << 2;
    const size_t r = e >> 10;
    const int    c = (int)(e & 1023);
    ushort4 a = *(const ushort4*)&x12[r * 2048 + c];
    ushort4 b = *(const ushort4*)&x12[r * 2048 + 1024 + c];
    ushort4 o;
    o.x = f2bf(silu_f(bf2f(a.x)) * bf2f(b.x));
    o.y = f2bf(silu_f(bf2f(a.y)) * bf2f(b.y));
    o.z = f2bf(silu_f(bf2f(a.z)) * bf2f(b.z));
    o.w = f2bf(silu_f(bf2f(a.w)) * bf2f(b.w));
    *(ushort4*)&out[r * 1024 + c] = o;
}

extern "C" void kernel_launch(void* const* d_in, const int* in_sizes, int n_in,
                              void* d_out, int out_size, void* d_ws, size_t ws_size,
                              hipStream_t stream)
{
    const float* x      = (const float*)d_in[0];
    const float* pb     = (const float*)d_in[2];
    const float* wq     = (const float*)d_in[3];
    const float* bq     = (const float*)d_in[4];
    const float* wk     = (const float*)d_in[5];
    const float* bk     = (const float*)d_in[6];
    const float* wv     = (const float*)d_in[7];
    const float* bv     = (const float*)d_in[8];
    const float* wu     = (const float*)d_in[9];
    const float* bu     = (const float*)d_in[10];
    const float* g_ams  = (const float*)d_in[11];
    const float* w0     = (const float*)d_in[12];
    const float* b0     = (const float*)d_in[13];
    const float* w1     = (const float*)d_in[14];
    const float* b1     = (const float*)d_in[15];
    const float* w2     = (const float*)d_in[16];
    const float* b2     = (const float*)d_in[17];
    const float* g_mffn = (const float*)d_in[18];
    float* OUT = (float*)d_out;            // fp32: o, then final output (in-place residual)

    const size_t MI = 1024 * 1024;
    u16* WS  = (u16*)d_ws;                 // 48 MB total
    u16* wqT = WS;                         // [1024][1024] bf16 each
    u16* wkT = WS + 1 * MI;
    u16* wvT = WS + 2 * MI;
    u16* wuT = WS + 3 * MI;
    u16* w0T = WS + 4 * MI;
    u16* w2T = WS + 5 * MI;
    u16* w1T = WS + 6 * MI;                // [2048][1024]
    u16* A0  = WS + 8 * MI;                // bf16 [4096][1024] each
    u16* A1  = WS + 12 * MI;
    u16* A2  = WS + 16 * MI;               // A2+A3 contiguous -> x12 [4096][2048]
    u16* A3  = WS + 20 * MI;
    (void)A3;

    dim3 blk(256);
    dim3 gT(16, 16), gT1(32, 16);
    dim3 gG(8, 32);                        // N=1024 MFMA GEMM
    dim3 gG2(16, 32);                      // N=2048

    // 0. weight prep (transpose + cast)
    transpose_cast_kernel<<<gT,  blk, 0, stream>>>(wq, wqT, 1024);
    transpose_cast_kernel<<<gT,  blk, 0, stream>>>(wk, wkT, 1024);
    transpose_cast_kernel<<<gT,  blk, 0, stream>>>(wv, wvT, 1024);
    transpose_cast_kernel<<<gT,  blk, 0, stream>>>(wu, wuT, 1024);
    transpose_cast_kernel<<<gT,  blk, 0, stream>>>(w0, w0T, 1024);
    transpose_cast_kernel<<<gT,  blk, 0, stream>>>(w2, w2T, 1024);
    transpose_cast_kernel<<<gT1, blk, 0, stream>>>(w1, w1T, 2048);

    // 1. xn = rmsnorm(x)*g_ams -> A0
    rmsnorm_kernel<<<ROWS, blk, 0, stream>>>(x, nullptr, g_ams, nullptr, A0);
    // 2. q -> A1, k -> A2, v -> A3
    gemm_mfma<<<gG, blk, 0, stream>>>(A0, wqT, bq, nullptr, A1, nullptr, D, 0);
    gemm_mfma<<<gG, blk, 0, stream>>>(A0, wkT, bk, nullptr, A2, nullptr, D, 0);
    gemm_mfma<<<gG, blk, 0, stream>>>(A0, wvT, bv, nullptr, A3, nullptr, D, 0);
    // 3. attention -> A1 (in-place over q)
    attn_kernel<<<dim3(S_ / 64, NH, B_), blk, 0, stream>>>(A1, A2, A3, pb, A1);
    // 4. u = silu(xn@wu+bu) -> A2 (k dead)
    gemm_mfma<<<gG, blk, 0, stream>>>(A0, wuT, bu, nullptr, A2, nullptr, D, 1);
    // 5. ams = rmsnorm(attn)*g_ams*u -> A0 (xn dead)
    rmsnorm_kernel<<<ROWS, blk, 0, stream>>>(nullptr, A1, g_ams, A2, A0);
    // 6. o = ams@w0 + b0 + x -> OUT fp32 (A1..A3 dead)
    gemm_mfma<<<gG, blk, 0, stream>>>(A0, w0T, b0, x, nullptr, OUT, D, 0);
    // 7. o_norm = rmsnorm(o)*g_mffn -> A1
    rmsnorm_kernel<<<ROWS, blk, 0, stream>>>(OUT, nullptr, g_mffn, nullptr, A1);
    // 8. x12 = o_norm@w1 + b1 -> A2 (bf16 [4096][2048])
    gemm_mfma<<<gG2, blk, 0, stream>>>(A1, w1T, b1, nullptr, A2, nullptr, 2 * D, 0);
    // 9. swiglu -> A0
    swiglu_kernel<<<ROWS * D / 1024, blk, 0, stream>>>(A2, A0);
    // 10. out = swiglu@w2 + b2 + o -> OUT (fp32, in-place residual: safe)
    gemm_mfma<<<gG, blk, 0, stream>>>(A0, w2T, b2, OUT, nullptr, OUT, D, 0);
}

// Round 5
// 493.420 us; speedup vs baseline: 3.3565x; 1.8004x over previous
//
#include <hip/hip_runtime.h>
#include <stdint.h>
#include <math.h>

// FuXi block on MI355X, round 5: MFMA bf16 GEMMs (m97 structure) + MFMA bf16
// attention (S^T=K.Q^T trick for b64 P-writes; V transposed via LDS; K frags
// pipelined from global). fp32 residual path in d_out. ws = 48 MB.

#define D    1024
#define NH   16
#define DH   64
#define B_   2
#define S_   2048
#define ROWS 4096
#define EPSR 1e-8f

typedef unsigned short u16;
typedef __attribute__((ext_vector_type(8))) short short8;
typedef __attribute__((ext_vector_type(4))) float f32x4;

__device__ __forceinline__ float bf2f(u16 u) {
    union { uint32_t i; float f; } c; c.i = ((uint32_t)u) << 16; return c.f;
}
__device__ __forceinline__ u16 f2bf(float f) {
    union { float f; uint32_t i; } c; c.f = f;
    uint32_t x = c.i;
    x += 0x7fffu + ((x >> 16) & 1u);
    return (u16)(x >> 16);
}
__device__ __forceinline__ float silu_f(float v) { return v / (1.0f + __expf(-v)); }

// ---------------- weight prep: fp32 W[K=1024][N] -> bf16 WT[N][1024] ----------------
__global__ __launch_bounds__(256) void transpose_cast_kernel(
    const float* __restrict__ W, u16* __restrict__ WTo, int N)
{
    __shared__ float T[64][65];
    const int tid = threadIdx.x;
    const int n0 = blockIdx.x << 6;
    const int k0 = blockIdx.y << 6;
    const int rr = tid >> 4;
    const int cc = (tid & 15) << 2;
#pragma unroll
    for (int l = 0; l < 4; ++l) {
        const int r = rr + (l << 4);
        float4 v = *(const float4*)&W[(size_t)(k0 + r) * N + n0 + cc];
        T[cc + 0][r] = v.x; T[cc + 1][r] = v.y;
        T[cc + 2][r] = v.z; T[cc + 3][r] = v.w;
    }
    __syncthreads();
    const int n  = tid >> 2;
    const int ks = (tid & 3) << 4;
#pragma unroll
    for (int m = 0; m < 4; ++m) {
        const int k = ks + (m << 2);
        float4 v = *(const float4*)&T[n][k];
        ushort4 o;
        o.x = f2bf(v.x); o.y = f2bf(v.y); o.z = f2bf(v.z); o.w = f2bf(v.w);
        *(ushort4*)&WTo[(size_t)(n0 + n) * 1024 + k0 + k] = o;
    }
}

// ---------------- RMSNorm: in fp32 OR bf16, optional bf16 mul, out bf16 ----------------
__global__ __launch_bounds__(256) void rmsnorm_kernel(
    const float* __restrict__ inf, const u16* __restrict__ inb,
    const float* __restrict__ g, const u16* __restrict__ mul,
    u16* __restrict__ out)
{
    const int row = blockIdx.x;
    const int tid = threadIdx.x;
    const size_t base = (size_t)row * D;
    const int c = tid << 2;
    float x0, x1, x2, x3;
    if (inb) {
        ushort4 xi = *(const ushort4*)&inb[base + c];
        x0 = bf2f(xi.x); x1 = bf2f(xi.y); x2 = bf2f(xi.z); x3 = bf2f(xi.w);
    } else {
        float4 xi = *(const float4*)&inf[base + c];
        x0 = xi.x; x1 = xi.y; x2 = xi.z; x3 = xi.w;
    }
    float ss = x0*x0 + x1*x1 + x2*x2 + x3*x3;
#pragma unroll
    for (int off = 32; off > 0; off >>= 1) ss += __shfl_down(ss, off, 64);
    __shared__ float red[4];
    if ((tid & 63) == 0) red[tid >> 6] = ss;
    __syncthreads();
    float r = rsqrtf((red[0] + red[1] + red[2] + red[3]) * (1.0f / D) + EPSR);
    float4 gv = *(const float4*)&g[c];
    float v0 = x0 * r * gv.x, v1 = x1 * r * gv.y, v2 = x2 * r * gv.z, v3 = x3 * r * gv.w;
    if (mul) {
        ushort4 mi = *(const ushort4*)&mul[base + c];
        v0 *= bf2f(mi.x); v1 *= bf2f(mi.y); v2 *= bf2f(mi.z); v3 *= bf2f(mi.w);
    }
    ushort4 o;
    o.x = f2bf(v0); o.y = f2bf(v1); o.z = f2bf(v2); o.w = f2bf(v3);
    *(ushort4*)&out[base + c] = o;
}

// ---------------- MFMA GEMM: C[4096,Nout] = A[4096,1024](bf16) @ WT^T ----------------
__global__ __launch_bounds__(256) void gemm_mfma(
    const u16* __restrict__ A, const u16* __restrict__ WT,
    const float* __restrict__ bias, const float* __restrict__ res,
    u16* __restrict__ outb, float* __restrict__ outf,
    int ldo, int act)
{
    __shared__ u16 As[128 * 32];
    __shared__ u16 Bs[128 * 32];
    const int tid  = threadIdx.x;
    const int wave = tid >> 6;
    const int lane = tid & 63;
    const int lm   = lane & 15;
    const int quad = lane >> 4;
    const int row0 = blockIdx.y << 7;
    const int col0 = blockIdx.x << 7;
    const int wr = (wave >> 1) << 6;
    const int wc = (wave & 1) << 6;

    const int srow = wave * 32 + (lane >> 2);
    const int skp  = (lane & 3) << 3;
    const u16* Ag = A  + (size_t)(row0 + srow) * 1024 + skp;
    const u16* Bg = WT + (size_t)(col0 + srow) * 1024 + skp;
    u16* Asd0 = &As[(wave * 32) * 32];
    u16* Asd1 = &As[(wave * 32 + 16) * 32];
    u16* Bsd0 = &Bs[(wave * 32) * 32];
    u16* Bsd1 = &Bs[(wave * 32 + 16) * 32];

    f32x4 acc[4][4] = {};

    for (int k0 = 0; k0 < 1024; k0 += 32) {
        __syncthreads();
        __builtin_amdgcn_global_load_lds(
            (const __attribute__((address_space(1))) void*)(Ag + k0),
            (__attribute__((address_space(3))) void*)Asd0, 16, 0, 0);
        __builtin_amdgcn_global_load_lds(
            (const __attribute__((address_space(1))) void*)(Ag + 16 * 1024 + k0),
            (__attribute__((address_space(3))) void*)Asd1, 16, 0, 0);
        __builtin_amdgcn_global_load_lds(
            (const __attribute__((address_space(1))) void*)(Bg + k0),
            (__attribute__((address_space(3))) void*)Bsd0, 16, 0, 0);
        __builtin_amdgcn_global_load_lds(
            (const __attribute__((address_space(1))) void*)(Bg + 16 * 1024 + k0),
            (__attribute__((address_space(3))) void*)Bsd1, 16, 0, 0);
        __syncthreads();
        short8 af[4], bf[4];
#pragma unroll
        for (int i = 0; i < 4; ++i)
            af[i] = *(const short8*)&As[(wr + i * 16 + lm) * 32 + quad * 8];
#pragma unroll
        for (int j = 0; j < 4; ++j)
            bf[j] = *(const short8*)&Bs[(wc + j * 16 + lm) * 32 + quad * 8];
#pragma unroll
        for (int i = 0; i < 4; ++i)
#pragma unroll
            for (int j = 0; j < 4; ++j)
                acc[i][j] = __builtin_amdgcn_mfma_f32_16x16x32_bf16(af[i], bf[j], acc[i][j], 0, 0, 0);
    }
#pragma unroll
    for (int j = 0; j < 4; ++j) {
        const int colg = col0 + wc + j * 16 + lm;
        const float bj = bias[colg];
#pragma unroll
        for (int i = 0; i < 4; ++i) {
#pragma unroll
            for (int r = 0; r < 4; ++r) {
                const int rowg = row0 + wr + i * 16 + quad * 4 + r;
                const size_t idx = (size_t)rowg * ldo + colg;
                float v = acc[i][j][r] + bj;
                if (act) v = silu_f(v);
                if (res) v += res[idx];
                if (outf) outf[idx] = v;
                else      outb[idx] = f2bf(v);
            }
        }
    }
}

// ---------------- MFMA SiLU attention ----------------
// Block = (b, h, 128 s-rows); 4 waves x 32 s-rows; t-loop 64/iter.
// S^T = K @ Q^T (m=t, n=s) so C-regs are t-consecutive -> ds_write_b64 of P.
// P[s][t] bf16 LDS (pitch 72); V^T[dh][t] bf16 LDS (pitch 72); pb col in LDS.
// Q frags persist in regs; K frags direct-from-global, pipelined 1 tile ahead.
// out may alias q (all Q loads precede loop; 2 syncs/iter separate them).
__global__ __launch_bounds__(256) void attn_mfma(
    const u16* __restrict__ q, const u16* __restrict__ k, const u16* __restrict__ v,
    const float* __restrict__ pb, u16* __restrict__ out)
{
    __shared__ u16 Vt[64 * 72];       // V^T [dh][t]
    __shared__ u16 Pl[128 * 72];      // P [s][t]
    __shared__ float pbl[2048];       // pb[:,h]
    const int tid  = threadIdx.x;
    const int wave = tid >> 6;
    const int lane = tid & 63;
    const int lm   = lane & 15;
    const int quad = lane >> 4;
    const int s0 = blockIdx.x << 7;
    const int h  = blockIdx.y;
    const int b  = blockIdx.z;
    const size_t base = (size_t)b * S_ * D + (size_t)h * DH;
    const int sw = wave << 5;          // wave s-offset (0/32/64/96)

    // pb column -> LDS
    for (int i = tid; i < S_; i += 256) pbl[i] = pb[(size_t)i * NH + h];

    // Q fragments (B-operand: n=s, k=dh), persist whole kernel
    short8 qf[2][2];
#pragma unroll
    for (int ns = 0; ns < 2; ++ns)
#pragma unroll
        for (int kk = 0; kk < 2; ++kk)
            qf[ns][kk] = *(const short8*)&q[base + (size_t)(s0 + sw + ns * 16 + lm) * D + kk * 32 + quad * 8];

    // K fragments for t0=0 (A-operand: m=t, k=dh)
    short8 kf[4][2];
#pragma unroll
    for (int mt = 0; mt < 4; ++mt)
#pragma unroll
        for (int kk = 0; kk < 2; ++kk)
            kf[mt][kk] = *(const short8*)&k[base + (size_t)(mt * 16 + lm) * D + kk * 32 + quad * 8];

    // V staging assignment: thread handles t-pair (2tp, 2tp+1) x 8 dh
    const int tp = tid & 31;
    const int d0 = (tid >> 5) << 3;

    f32x4 accO[2][4] = {};
    __syncthreads();   // pbl visible

    for (int t0 = 0; t0 < S_; t0 += 64) {
        // V loads for this tile (issue early, consumed after sync)
        ushort4 v0a = *(const ushort4*)&v[base + (size_t)(t0 + 2 * tp) * D + d0];
        ushort4 v0b = *(const ushort4*)&v[base + (size_t)(t0 + 2 * tp) * D + d0 + 4];
        ushort4 v1a = *(const ushort4*)&v[base + (size_t)(t0 + 2 * tp + 1) * D + d0];
        ushort4 v1b = *(const ushort4*)&v[base + (size_t)(t0 + 2 * tp + 1) * D + d0 + 4];
        // S^T = K @ Q^T
        f32x4 st[4][2] = {};
#pragma unroll
        for (int mt = 0; mt < 4; ++mt)
#pragma unroll
            for (int ns = 0; ns < 2; ++ns)
#pragma unroll
                for (int kk = 0; kk < 2; ++kk)
                    st[mt][ns] = __builtin_amdgcn_mfma_f32_16x16x32_bf16(kf[mt][kk], qf[ns][kk], st[mt][ns], 0, 0, 0);
        __syncthreads();   // prev-iter P/Vt reads done
        // stage V^T: pack (t,t+1) pairs per dh -> b32 writes
        {
            const u16 va[8] = {v0a.x, v0a.y, v0a.z, v0a.w, v0b.x, v0b.y, v0b.z, v0b.w};
            const u16 vb[8] = {v1a.x, v1a.y, v1a.z, v1a.w, v1b.x, v1b.y, v1b.z, v1b.w};
#pragma unroll
            for (int i = 0; i < 8; ++i) {
                uint32_t pk = (uint32_t)va[i] | ((uint32_t)vb[i] << 16);
                *(uint32_t*)&Vt[(d0 + i) * 72 + 2 * tp] = pk;
            }
        }
        // P = silu(0.125*S + pb), packed ushort4 along t
#pragma unroll
        for (int mt = 0; mt < 4; ++mt) {
            const int tl = mt * 16 + quad * 4;
            float4 pbv = *(const float4*)&pbl[t0 + tl];
            const float pbr[4] = {pbv.x, pbv.y, pbv.z, pbv.w};
#pragma unroll
            for (int ns = 0; ns < 2; ++ns) {
                ushort4 pk;
                pk.x = f2bf(silu_f(fmaf(st[mt][ns][0], 0.125f, pbr[0])));
                pk.y = f2bf(silu_f(fmaf(st[mt][ns][1], 0.125f, pbr[1])));
                pk.z = f2bf(silu_f(fmaf(st[mt][ns][2], 0.125f, pbr[2])));
                pk.w = f2bf(silu_f(fmaf(st[mt][ns][3], 0.125f, pbr[3])));
                *(ushort4*)&Pl[(sw + ns * 16 + lm) * 72 + tl] = pk;
            }
        }
        __syncthreads();   // P + V^T visible
        // prefetch next K tile (overlaps PV)
        if (t0 + 64 < S_) {
#pragma unroll
            for (int mt = 0; mt < 4; ++mt)
#pragma unroll
                for (int kk = 0; kk < 2; ++kk)
                    kf[mt][kk] = *(const short8*)&k[base + (size_t)(t0 + 64 + mt * 16 + lm) * D + kk * 32 + quad * 8];
        }
        // O += P @ V  (m=s, n=dh, k=t)
        short8 pf[2][2], vf[4][2];
#pragma unroll
        for (int mi = 0; mi < 2; ++mi)
#pragma unroll
            for (int kk = 0; kk < 2; ++kk)
                pf[mi][kk] = *(const short8*)&Pl[(sw + mi * 16 + lm) * 72 + kk * 32 + quad * 8];
#pragma unroll
        for (int nj = 0; nj < 4; ++nj)
#pragma unroll
            for (int kk = 0; kk < 2; ++kk)
                vf[nj][kk] = *(const short8*)&Vt[(nj * 16 + lm) * 72 + kk * 32 + quad * 8];
#pragma unroll
        for (int mi = 0; mi < 2; ++mi)
#pragma unroll
            for (int nj = 0; nj < 4; ++nj)
#pragma unroll
                for (int kk = 0; kk < 2; ++kk)
                    accO[mi][nj] = __builtin_amdgcn_mfma_f32_16x16x32_bf16(pf[mi][kk], vf[nj][kk], accO[mi][nj], 0, 0, 0);
    }
    // store O: C-layout col=dh_local, row=s_local
#pragma unroll
    for (int mi = 0; mi < 2; ++mi)
#pragma unroll
        for (int nj = 0; nj < 4; ++nj)
#pragma unroll
            for (int r = 0; r < 4; ++r) {
                const int s = s0 + sw + mi * 16 + quad * 4 + r;
                out[base + (size_t)s * D + nj * 16 + lm] = f2bf(accO[mi][nj][r]);
            }
}

// ---------------- SwiGLU: x12 bf16 [4096][2048] -> out bf16 [4096][1024] ----------------
__global__ __launch_bounds__(256) void swiglu_kernel(
    const u16* __restrict__ x12, u16* __restrict__ out)
{
    const size_t e = ((size_t)blockIdx.x * 256 + threadIdx.x) << 2;
    const size_t r = e >> 10;
    const int    c = (int)(e & 1023);
    ushort4 a = *(const ushort4*)&x12[r * 2048 + c];
    ushort4 b = *(const ushort4*)&x12[r * 2048 + 1024 + c];
    ushort4 o;
    o.x = f2bf(silu_f(bf2f(a.x)) * bf2f(b.x));
    o.y = f2bf(silu_f(bf2f(a.y)) * bf2f(b.y));
    o.z = f2bf(silu_f(bf2f(a.z)) * bf2f(b.z));
    o.w = f2bf(silu_f(bf2f(a.w)) * bf2f(b.w));
    *(ushort4*)&out[r * 1024 + c] = o;
}

extern "C" void kernel_launch(void* const* d_in, const int* in_sizes, int n_in,
                              void* d_out, int out_size, void* d_ws, size_t ws_size,
                              hipStream_t stream)
{
    const float* x      = (const float*)d_in[0];
    const float* pb     = (const float*)d_in[2];
    const float* wq     = (const float*)d_in[3];
    const float* bq     = (const float*)d_in[4];
    const float* wk     = (const float*)d_in[5];
    const float* bk     = (const float*)d_in[6];
    const float* wv     = (const float*)d_in[7];
    const float* bv     = (const float*)d_in[8];
    const float* wu     = (const float*)d_in[9];
    const float* bu     = (const float*)d_in[10];
    const float* g_ams  = (const float*)d_in[11];
    const float* w0     = (const float*)d_in[12];
    const float* b0     = (const float*)d_in[13];
    const float* w1     = (const float*)d_in[14];
    const float* b1     = (const float*)d_in[15];
    const float* w2     = (const float*)d_in[16];
    const float* b2     = (const float*)d_in[17];
    const float* g_mffn = (const float*)d_in[18];
    float* OUT = (float*)d_out;

    const size_t MI = 1024 * 1024;
    u16* WS  = (u16*)d_ws;                 // 48 MB total
    u16* wqT = WS;
    u16* wkT = WS + 1 * MI;
    u16* wvT = WS + 2 * MI;
    u16* wuT = WS + 3 * MI;
    u16* w0T = WS + 4 * MI;
    u16* w2T = WS + 5 * MI;
    u16* w1T = WS + 6 * MI;                // [2048][1024]
    u16* A0  = WS + 8 * MI;
    u16* A1  = WS + 12 * MI;
    u16* A2  = WS + 16 * MI;               // A2+A3 contiguous -> x12 [4096][2048]
    u16* A3  = WS + 20 * MI;

    dim3 blk(256);
    dim3 gT(16, 16), gT1(32, 16);
    dim3 gG(8, 32);
    dim3 gG2(16, 32);

    transpose_cast_kernel<<<gT,  blk, 0, stream>>>(wq, wqT, 1024);
    transpose_cast_kernel<<<gT,  blk, 0, stream>>>(wk, wkT, 1024);
    transpose_cast_kernel<<<gT,  blk, 0, stream>>>(wv, wvT, 1024);
    transpose_cast_kernel<<<gT,  blk, 0, stream>>>(wu, wuT, 1024);
    transpose_cast_kernel<<<gT,  blk, 0, stream>>>(w0, w0T, 1024);
    transpose_cast_kernel<<<gT,  blk, 0, stream>>>(w2, w2T, 1024);
    transpose_cast_kernel<<<gT1, blk, 0, stream>>>(w1, w1T, 2048);

    // 1. xn = rmsnorm(x)*g_ams -> A0
    rmsnorm_kernel<<<ROWS, blk, 0, stream>>>(x, nullptr, g_ams, nullptr, A0);
    // 2. q -> A1, k -> A2, v -> A3
    gemm_mfma<<<gG, blk, 0, stream>>>(A0, wqT, bq, nullptr, A1, nullptr, D, 0);
    gemm_mfma<<<gG, blk, 0, stream>>>(A0, wkT, bk, nullptr, A2, nullptr, D, 0);
    gemm_mfma<<<gG, blk, 0, stream>>>(A0, wvT, bv, nullptr, A3, nullptr, D, 0);
    // 3. attention -> A1 (in-place over q)
    attn_mfma<<<dim3(S_ / 128, NH, B_), blk, 0, stream>>>(A1, A2, A3, pb, A1);
    // 4. u = silu(xn@wu+bu) -> A2 (k dead)
    gemm_mfma<<<gG, blk, 0, stream>>>(A0, wuT, bu, nullptr, A2, nullptr, D, 1);
    // 5. ams = rmsnorm(attn)*g_ams*u -> A0 (xn dead)
    rmsnorm_kernel<<<ROWS, blk, 0, stream>>>(nullptr, A1, g_ams, A2, A0);
    // 6. o = ams@w0 + b0 + x -> OUT fp32
    gemm_mfma<<<gG, blk, 0, stream>>>(A0, w0T, b0, x, nullptr, OUT, D, 0);
    // 7. o_norm = rmsnorm(o)*g_mffn -> A1
    rmsnorm_kernel<<<ROWS, blk, 0, stream>>>(OUT, nullptr, g_mffn, nullptr, A1);
    // 8. x12 = o_norm@w1 + b1 -> A2 (bf16 [4096][2048])
    gemm_mfma<<<gG2, blk, 0, stream>>>(A1, w1T, b1, nullptr, A2, nullptr, 2 * D, 0);
    // 9. swiglu -> A0
    swiglu_kernel<<<ROWS * D / 1024, blk, 0, stream>>>(A2, A0);
    // 10. out = swiglu@w2 + b2 + o -> OUT (fp32, in-place residual)
    gemm_mfma<<<gG, blk, 0, stream>>>(A0, w2T, b2, OUT, nullptr, OUT, D, 0);
    (void)A3; (void)ws_size; (void)in_sizes; (void)n_in; (void)out_size;
}